// Round 1
// baseline (98.799 us; speedup 1.0000x reference)
//
#include <hip/hip_runtime.h>
#include <math.h>

#define B_ 8
#define M_ 10
#define S_ 200
#define N_ 2048
#define L_ 128
#define BETA_ 0.01f
#define EPS_ 1e-6f

__device__ __forceinline__ float fexp_(float x, float p) {
    float s = (x > 0.f) ? 1.f : ((x < 0.f) ? -1.f : 0.f);
    return s * powf(fmaxf(fabsf(x), EPS_), p);
}

// ---------------------------------------------------------------------------
// Kernel 0: per-(b,m) rotation matrix + per-(b,m,s) deformed surface points
// ---------------------------------------------------------------------------
__global__ void prep_k(const float* __restrict__ rot, const float* __restrict__ size,
                       const float* __restrict__ shp, const float* __restrict__ def,
                       const float* __restrict__ etas, const float* __restrict__ omegas,
                       float* __restrict__ wsR, float4* __restrict__ wsPts)
{
    int bm = blockIdx.x;      // 0..B*M-1
    int t = threadIdx.x;
    if (t == 0) {
        float w = rot[bm*4+0], x = rot[bm*4+1], y = rot[bm*4+2], z = rot[bm*4+3];
        float inv = 1.f / sqrtf(w*w + x*x + y*y + z*z);
        w *= inv; x *= inv; y *= inv; z *= inv;
        float* Rm = wsR + bm*9;
        Rm[0] = 1.f - 2.f*(y*y + z*z); Rm[1] = 2.f*(x*y - w*z);       Rm[2] = 2.f*(x*z + w*y);
        Rm[3] = 2.f*(x*y + w*z);       Rm[4] = 1.f - 2.f*(x*x + z*z); Rm[5] = 2.f*(y*z - w*x);
        Rm[6] = 2.f*(x*z - w*y);       Rm[7] = 2.f*(y*z + w*x);       Rm[8] = 1.f - 2.f*(x*x + y*y);
    }
    if (t < S_) {
        float a1 = size[bm*3+0], a2 = size[bm*3+1], a3 = size[bm*3+2];
        float e1 = shp[bm*2+0],  e2 = shp[bm*2+1];
        float d0 = def[bm*2+0],  d1 = def[bm*2+1];
        float eta = etas[bm*S_+t], om = omegas[bm*S_+t];
        float ce = cosf(eta), se = sinf(eta);
        float co = cosf(om),  so = sinf(om);
        float fce = fexp_(ce, e1), fse = fexp_(se, e1);
        float fco = fexp_(co, e2), fso = fexp_(so, e2);
        float px = a1 * fce * fco;
        float py = a2 * fce * fso;
        float pz = a3 * fse;
        float fr = pz / a3;
        px *= d0*fr + 1.f;
        py *= d1*fr + 1.f;
        wsPts[bm*S_+t] = make_float4(px, py, pz, 0.f);
    }
}

// ---------------------------------------------------------------------------
// Kernel A: V[b,n,m] = min_s dist, sort over M, Fs weighting -> pcl_to_prim sum
// grid: B * (N/64) blocks, 256 threads. 4 lanes (sg) share one n, each covers
// 50 s-values; shfl_xor min-combine.
// ---------------------------------------------------------------------------
__global__ __launch_bounds__(256) void pcl_k(const float* __restrict__ ipts,
                                             const float* __restrict__ trans,
                                             const float* __restrict__ probs,
                                             const float* __restrict__ wsR,
                                             const float4* __restrict__ wsPts,
                                             float* __restrict__ acc)
{
    constexpr int CH = N_ / 64;    // 32 chunks of 64 points
    int b = blockIdx.x / CH;
    int chunk = blockIdx.x % CH;
    int t = threadIdx.x;

    __shared__ float4 sPts[M_*S_];   // 32 KB
    __shared__ float  sR[M_*9];
    __shared__ float  sT[M_*3];
    __shared__ float  sP[M_];

    const float4* gp = wsPts + b*M_*S_;
    for (int i = t; i < M_*S_; i += 256) sPts[i] = gp[i];
    if (t < M_*9) sR[t] = wsR[b*M_*9 + t];
    if (t < M_*3) sT[t] = trans[b*M_*3 + t];
    if (t < M_)   sP[t] = probs[b*M_ + t];
    __syncthreads();

    int nl = t >> 2;        // 0..63
    int sg = t & 3;         // s-group
    int n = chunk*64 + nl;
    float x = ipts[(b*N_+n)*3 + 0];
    float y = ipts[(b*N_+n)*3 + 1];
    float z = ipts[(b*N_+n)*3 + 2];

    float V[M_], P[M_];
    #pragma unroll
    for (int m = 0; m < M_; ++m) {
        float r00 = sR[m*9+0], r01 = sR[m*9+1], r02 = sR[m*9+2];
        float r10 = sR[m*9+3], r11 = sR[m*9+4], r12 = sR[m*9+5];
        float r20 = sR[m*9+6], r21 = sR[m*9+7], r22 = sR[m*9+8];
        float cx = x - sT[m*3+0], cy = y - sT[m*3+1], cz = z - sT[m*3+2];
        float X0 = r00*cx + r01*cy + r02*cz;
        float X1 = r10*cx + r11*cy + r12*cz;
        float X2 = r20*cx + r21*cy + r22*cz;
        float vm = 3.4e38f;
        int s0 = m*S_ + sg*50;
        #pragma unroll 10
        for (int s = 0; s < 50; ++s) {
            float4 p = sPts[s0 + s];
            float dx = p.x - X0, dy = p.y - X1, dz = p.z - X2;
            float d = dx*dx + dy*dy + dz*dz;
            vm = fminf(vm, d);
        }
        V[m] = vm;
        P[m] = sP[m];
    }
    // combine the 4 s-groups
    #pragma unroll
    for (int m = 0; m < M_; ++m) {
        V[m] = fminf(V[m], __shfl_xor(V[m], 1));
        V[m] = fminf(V[m], __shfl_xor(V[m], 2));
    }
    // in-register bubble sort ascending by V (indices all compile-time)
    #pragma unroll
    for (int i = 0; i < M_-1; ++i) {
        #pragma unroll
        for (int j = 0; j < M_-1-i; ++j) {
            if (V[j] > V[j+1]) {
                float tv = V[j]; V[j] = V[j+1]; V[j+1] = tv;
                float tp = P[j]; P[j] = P[j+1]; P[j+1] = tp;
            }
        }
    }
    float cum = 1.f, sum = 0.f;
    #pragma unroll
    for (int i = 0; i < M_; ++i) {
        sum += P[i] * cum * V[i];
        cum *= (1.f - P[i]);
    }
    float contrib = (sg == 0) ? sum : 0.f;
    #pragma unroll
    for (int o = 1; o < 64; o <<= 1) contrib += __shfl_xor(contrib, o);

    __shared__ float sSum[4];
    int wave = t >> 6, lane = t & 63;
    if (lane == 0) sSum[wave] = contrib;
    __syncthreads();
    if (t == 0) atomicAdd(acc, sSum[0] + sSum[1] + sSum[2] + sSum[3]);
}

// ---------------------------------------------------------------------------
// Kernel B: smin[b,m,s] = min_n dist. grid: B*M*8 blocks (tiles of 256 n),
// 256 threads. Stage rotated Xt tile in LDS; lane s loops tile; atomicMin.
// ---------------------------------------------------------------------------
__global__ __launch_bounds__(256) void smin_k(const float* __restrict__ ipts,
                                              const float* __restrict__ trans,
                                              const float* __restrict__ wsR,
                                              const float4* __restrict__ wsPts,
                                              unsigned int* __restrict__ smin)
{
    constexpr int CH2 = N_ / 256;  // 8
    int bm = blockIdx.x / CH2;
    int chunk = blockIdx.x % CH2;
    int b = bm / M_;
    int t = threadIdx.x;

    __shared__ float4 sXt[256];

    float r00 = wsR[bm*9+0], r01 = wsR[bm*9+1], r02 = wsR[bm*9+2];
    float r10 = wsR[bm*9+3], r11 = wsR[bm*9+4], r12 = wsR[bm*9+5];
    float r20 = wsR[bm*9+6], r21 = wsR[bm*9+7], r22 = wsR[bm*9+8];
    float tx = trans[bm*3+0], ty = trans[bm*3+1], tz = trans[bm*3+2];

    int n = chunk*256 + t;
    float x = ipts[(b*N_+n)*3 + 0] - tx;
    float y = ipts[(b*N_+n)*3 + 1] - ty;
    float z = ipts[(b*N_+n)*3 + 2] - tz;
    sXt[t] = make_float4(r00*x + r01*y + r02*z,
                         r10*x + r11*y + r12*z,
                         r20*x + r21*y + r22*z, 0.f);
    __syncthreads();

    if (t < S_) {
        float4 p = wsPts[bm*S_ + t];
        float vm = 3.4e38f;
        #pragma unroll 8
        for (int j = 0; j < 256; ++j) {
            float4 q = sXt[j];
            float dx = p.x - q.x, dy = p.y - q.y, dz = p.z - q.z;
            float d = dx*dx + dy*dy + dz*dz;
            vm = fminf(vm, d);
        }
        atomicMin(&smin[bm*S_ + t], __float_as_uint(vm));  // vm >= 0 -> uint order ok
    }
}

// ---------------------------------------------------------------------------
// Kernel C: finalize — prim_to_pcl from smin, KLD, combine outputs.
// ---------------------------------------------------------------------------
__global__ __launch_bounds__(256) void final_k(const unsigned int* __restrict__ smin,
                                               const float* __restrict__ probs,
                                               const float* __restrict__ mu,
                                               const float* __restrict__ logvar,
                                               const float* __restrict__ acc,
                                               float* __restrict__ out)
{
    int t = threadIdx.x;
    float s1 = 0.f;
    for (int i = t; i < B_*M_*S_; i += 256) {
        int bm = i / S_;
        s1 += __uint_as_float(smin[i]) * probs[bm];
    }
    float s2 = 0.f;
    for (int i = t; i < B_*L_; i += 256) {
        float muv = mu[i], lv = logvar[i];
        s2 += -0.5f * (1.f + lv - muv*muv - expf(lv));
    }
    #pragma unroll
    for (int o = 1; o < 64; o <<= 1) {
        s1 += __shfl_xor(s1, o);
        s2 += __shfl_xor(s2, o);
    }
    __shared__ float r1[4], r2[4];
    int wave = t >> 6, lane = t & 63;
    if (lane == 0) { r1[wave] = s1; r2[wave] = s2; }
    __syncthreads();
    if (t == 0) {
        float S1 = r1[0] + r1[1] + r1[2] + r1[3];
        float S2 = r2[0] + r2[1] + r2[2] + r2[3];
        float prim_to_pcl = S1 / (float)(B_ * S_);
        float kld = S2 / (float)B_;
        float pcl_to_prim = acc[0] / (float)(B_ * N_);
        float prims = pcl_to_prim + prim_to_pcl;
        out[0] = prims + BETA_ * kld;   // total
        out[1] = prims;
        out[2] = 0.f;                   // regs
        out[3] = kld;
    }
}

extern "C" void kernel_launch(void* const* d_in, const int* in_sizes, int n_in,
                              void* d_out, int out_size, void* d_ws, size_t ws_size,
                              hipStream_t stream) {
    const float* ipts    = (const float*)d_in[0];
    const float* trans   = (const float*)d_in[1];
    const float* rot     = (const float*)d_in[2];
    const float* size    = (const float*)d_in[3];
    const float* shp     = (const float*)d_in[4];
    const float* def     = (const float*)d_in[5];
    const float* probs   = (const float*)d_in[6];
    const float* etas    = (const float*)d_in[7];
    const float* omegas  = (const float*)d_in[8];
    const float* mu      = (const float*)d_in[9];
    const float* logvar  = (const float*)d_in[10];
    float* out = (float*)d_out;

    char* ws = (char*)d_ws;
    unsigned int* smin = (unsigned int*)ws;          // B*M*S*4   = 64000 B
    float* acc   = (float*)(ws + 64000);             // 64 B (accumulators)
    float* wsR   = (float*)(ws + 64064);             // B*M*9*4   = 2880 B
    float4* wsPts = (float4*)(ws + 66944);           // B*M*S*16  = 256000 B

    // init: smin -> large positive float bits; acc -> 0 (graph-capture-safe)
    hipMemsetAsync(smin, 0x7F, (size_t)(B_*M_*S_*4), stream);
    hipMemsetAsync(acc, 0, 64, stream);

    prep_k<<<B_*M_, 256, 0, stream>>>(rot, size, shp, def, etas, omegas, wsR, wsPts);
    pcl_k<<<B_*(N_/64), 256, 0, stream>>>(ipts, trans, probs, wsR, wsPts, acc);
    smin_k<<<B_*M_*(N_/256), 256, 0, stream>>>(ipts, trans, wsR, wsPts, smin);
    final_k<<<1, 256, 0, stream>>>(smin, probs, mu, logvar, acc, out);
}

// Round 2
// 71.751 us; speedup vs baseline: 1.3770x; 1.3770x over previous
//
#include <hip/hip_runtime.h>
#include <math.h>

#define B_ 8
#define M_ 10
#define S_ 200
#define N_ 2048
#define L_ 128
#define BETA_ 0.01f
#define EPS_ 1e-6f
#define INF_U 0x7F7F7F7Fu

__device__ __forceinline__ float fexp_(float x, float p) {
    float s = (x > 0.f) ? 1.f : ((x < 0.f) ? -1.f : 0.f);
    return s * powf(fmaxf(fabsf(x), EPS_), p);
}

// ---------------------------------------------------------------------------
// Kernel 0: rotation matrices + deformed surface points + ws init (smin, acc)
// grid: 80 blocks x 256
// ---------------------------------------------------------------------------
__global__ void prep_k(const float* __restrict__ rot, const float* __restrict__ size,
                       const float* __restrict__ shp, const float* __restrict__ def,
                       const float* __restrict__ etas, const float* __restrict__ omegas,
                       float* __restrict__ wsR, float4* __restrict__ wsPts,
                       unsigned int* __restrict__ gmin, float* __restrict__ acc)
{
    int bm = blockIdx.x;      // 0..B*M-1
    int t = threadIdx.x;
    int gid = bm * 256 + t;
    if (gid < B_*M_*S_) gmin[gid] = INF_U;
    if (gid == 0) acc[0] = 0.f;

    if (t == 0) {
        float w = rot[bm*4+0], x = rot[bm*4+1], y = rot[bm*4+2], z = rot[bm*4+3];
        float inv = 1.f / sqrtf(w*w + x*x + y*y + z*z);
        w *= inv; x *= inv; y *= inv; z *= inv;
        float* Rm = wsR + bm*9;
        Rm[0] = 1.f - 2.f*(y*y + z*z); Rm[1] = 2.f*(x*y - w*z);       Rm[2] = 2.f*(x*z + w*y);
        Rm[3] = 2.f*(x*y + w*z);       Rm[4] = 1.f - 2.f*(x*x + z*z); Rm[5] = 2.f*(y*z - w*x);
        Rm[6] = 2.f*(x*z - w*y);       Rm[7] = 2.f*(y*z + w*x);       Rm[8] = 1.f - 2.f*(x*x + y*y);
    }
    if (t < S_) {
        float a1 = size[bm*3+0], a2 = size[bm*3+1], a3 = size[bm*3+2];
        float e1 = shp[bm*2+0],  e2 = shp[bm*2+1];
        float d0 = def[bm*2+0],  d1 = def[bm*2+1];
        float eta = etas[bm*S_+t], om = omegas[bm*S_+t];
        float ce = cosf(eta), se = sinf(eta);
        float co = cosf(om),  so = sinf(om);
        float fce = fexp_(ce, e1), fse = fexp_(se, e1);
        float fco = fexp_(co, e2), fso = fexp_(so, e2);
        float px = a1 * fce * fco;
        float py = a2 * fce * fso;
        float pz = a3 * fse;
        float fr = pz / a3;
        px *= d0*fr + 1.f;
        py *= d1*fr + 1.f;
        wsPts[bm*S_+t] = make_float4(px, py, pz, 0.f);
    }
}

// ---------------------------------------------------------------------------
// Fused dist kernel: one pass over dist[b,m,s,n], both reductions.
//   grid = B * (N/32) = 512 blocks, 256 threads.
//   thread: sg = t&15 (s-group, 13 s each w/ clamp), nl = t>>4 (2 points each).
//   V (min over s) -> shfl over sg bits -> sort -> Fs weighting -> atomicAdd.
//   smin (min over n) -> shfl over nl bits (16,32) -> LDS atomicMin -> global.
// ---------------------------------------------------------------------------
__global__ __launch_bounds__(256) void fused_k(const float* __restrict__ ipts,
                                               const float* __restrict__ trans,
                                               const float* __restrict__ probs,
                                               const float* __restrict__ wsR,
                                               const float4* __restrict__ wsPts,
                                               unsigned int* __restrict__ gmin,
                                               float* __restrict__ acc)
{
    constexpr int CH = N_ / 32;    // 64 chunks of 32 points
    int b = blockIdx.x / CH;
    int chunk = blockIdx.x % CH;
    int t = threadIdx.x;

    __shared__ float4 sPts[M_*S_];       // 32 KB
    __shared__ unsigned int sMin[M_*S_]; // 8 KB
    __shared__ float  sR[M_*9];
    __shared__ float  sT[M_*3];
    __shared__ float  sP[M_];

    const float4* gp = wsPts + b*M_*S_;
    for (int i = t; i < M_*S_; i += 256) { sPts[i] = gp[i]; sMin[i] = INF_U; }
    if (t < M_*9) sR[t] = wsR[b*M_*9 + t];
    if (t < M_*3) sT[t] = trans[b*M_*3 + t];
    if (t < M_)   sP[t] = probs[b*M_ + t];
    __syncthreads();

    int sg = t & 15;
    int nl = t >> 4;             // 0..15
    int nl_w = nl & 3;           // nl within wave
    int n0 = chunk*32 + nl*2;
    float x0 = ipts[(b*N_+n0)*3 + 0];
    float y0 = ipts[(b*N_+n0)*3 + 1];
    float z0 = ipts[(b*N_+n0)*3 + 2];
    float x1 = ipts[(b*N_+n0+1)*3 + 0];
    float y1 = ipts[(b*N_+n0+1)*3 + 1];
    float z1 = ipts[(b*N_+n0+1)*3 + 2];
    int sbeg = sg*12 + (sg < 8 ? sg : 8);   // 13 s for sg<8, 12 (+1 dup) for sg>=8

    float V0[M_], V1[M_];
    #pragma unroll
    for (int m = 0; m < M_; ++m) {
        float r00 = sR[m*9+0], r01 = sR[m*9+1], r02 = sR[m*9+2];
        float r10 = sR[m*9+3], r11 = sR[m*9+4], r12 = sR[m*9+5];
        float r20 = sR[m*9+6], r21 = sR[m*9+7], r22 = sR[m*9+8];
        float tx = sT[m*3+0], ty = sT[m*3+1], tz = sT[m*3+2];
        float cx = x0 - tx, cy = y0 - ty, cz = z0 - tz;
        float X00 = r00*cx + r01*cy + r02*cz;
        float X01 = r10*cx + r11*cy + r12*cz;
        float X02 = r20*cx + r21*cy + r22*cz;
        cx = x1 - tx; cy = y1 - ty; cz = z1 - tz;
        float X10 = r00*cx + r01*cy + r02*cz;
        float X11 = r10*cx + r11*cy + r12*cz;
        float X12 = r20*cx + r21*cy + r22*cz;
        float vm0 = 3.4e38f, vm1 = 3.4e38f;
        int base = m*S_;
        #pragma unroll
        for (int k = 0; k < 13; ++k) {
            int s = sbeg + k;
            s = (s > S_-1) ? S_-1 : s;      // dup is harmless under min
            float4 p = sPts[base + s];
            float dx = p.x - X00, dy = p.y - X01, dz = p.z - X02;
            float d0 = dx*dx + dy*dy + dz*dz;
            dx = p.x - X10; dy = p.y - X11; dz = p.z - X12;
            float d1 = dx*dx + dy*dy + dz*dz;
            vm0 = fminf(vm0, d0);
            vm1 = fminf(vm1, d1);
            float dm = fminf(d0, d1);
            dm = fminf(dm, __shfl_xor(dm, 16));
            dm = fminf(dm, __shfl_xor(dm, 32));
            if (nl_w == 0) atomicMin(&sMin[base + s], __float_as_uint(dm));
        }
        V0[m] = vm0; V1[m] = vm1;
    }

    // min over the 16 s-groups (sg = bits 0..3 of t)
    #pragma unroll
    for (int m = 0; m < M_; ++m) {
        #pragma unroll
        for (int o = 1; o < 16; o <<= 1) {
            V0[m] = fminf(V0[m], __shfl_xor(V0[m], o));
            V1[m] = fminf(V1[m], __shfl_xor(V1[m], o));
        }
    }

    // sort + Fs weighting for both points (uniform across lanes, no divergence)
    float sum01 = 0.f;
    {
        float P[M_];
        #pragma unroll
        for (int m = 0; m < M_; ++m) P[m] = sP[m];
        #pragma unroll
        for (int i = 0; i < M_-1; ++i)
            #pragma unroll
            for (int j = 0; j < M_-1-i; ++j)
                if (V0[j] > V0[j+1]) {
                    float tv = V0[j]; V0[j] = V0[j+1]; V0[j+1] = tv;
                    float tp = P[j];  P[j]  = P[j+1];  P[j+1]  = tp;
                }
        float cum = 1.f;
        #pragma unroll
        for (int i = 0; i < M_; ++i) { sum01 += P[i] * cum * V0[i]; cum *= (1.f - P[i]); }
    }
    {
        float P[M_];
        #pragma unroll
        for (int m = 0; m < M_; ++m) P[m] = sP[m];
        #pragma unroll
        for (int i = 0; i < M_-1; ++i)
            #pragma unroll
            for (int j = 0; j < M_-1-i; ++j)
                if (V1[j] > V1[j+1]) {
                    float tv = V1[j]; V1[j] = V1[j+1]; V1[j+1] = tv;
                    float tp = P[j];  P[j]  = P[j+1];  P[j+1]  = tp;
                }
        float cum = 1.f;
        #pragma unroll
        for (int i = 0; i < M_; ++i) { sum01 += P[i] * cum * V1[i]; cum *= (1.f - P[i]); }
    }

    float contrib = (sg == 0) ? sum01 : 0.f;
    #pragma unroll
    for (int o = 1; o < 64; o <<= 1) contrib += __shfl_xor(contrib, o);

    __shared__ float sSum[4];
    int wave = t >> 6, lane = t & 63;
    if (lane == 0) sSum[wave] = contrib;
    __syncthreads();
    if (t == 0) atomicAdd(acc, sSum[0] + sSum[1] + sSum[2] + sSum[3]);

    // merge per-block smin into global
    for (int i = t; i < M_*S_; i += 256)
        atomicMin(&gmin[b*M_*S_ + i], sMin[i]);
}

// ---------------------------------------------------------------------------
// Finalize: prim_to_pcl from gmin, KLD, combine. 1 block x 1024.
// ---------------------------------------------------------------------------
__global__ __launch_bounds__(1024) void final_k(const unsigned int* __restrict__ gmin,
                                                const float* __restrict__ probs,
                                                const float* __restrict__ mu,
                                                const float* __restrict__ logvar,
                                                const float* __restrict__ acc,
                                                float* __restrict__ out)
{
    int t = threadIdx.x;
    float s1 = 0.f;
    for (int i = t; i < B_*M_*S_; i += 1024) {
        int bm = i / S_;
        s1 += __uint_as_float(gmin[i]) * probs[bm];
    }
    float s2 = 0.f;
    for (int i = t; i < B_*L_; i += 1024) {
        float muv = mu[i], lv = logvar[i];
        s2 += -0.5f * (1.f + lv - muv*muv - expf(lv));
    }
    #pragma unroll
    for (int o = 1; o < 64; o <<= 1) {
        s1 += __shfl_xor(s1, o);
        s2 += __shfl_xor(s2, o);
    }
    __shared__ float r1[16], r2[16];
    int wave = t >> 6, lane = t & 63;
    if (lane == 0) { r1[wave] = s1; r2[wave] = s2; }
    __syncthreads();
    if (t == 0) {
        float S1 = 0.f, S2 = 0.f;
        #pragma unroll
        for (int w = 0; w < 16; ++w) { S1 += r1[w]; S2 += r2[w]; }
        float prim_to_pcl = S1 / (float)(B_ * S_);
        float kld = S2 / (float)B_;
        float pcl_to_prim = acc[0] / (float)(B_ * N_);
        float prims = pcl_to_prim + prim_to_pcl;
        out[0] = prims + BETA_ * kld;   // total
        out[1] = prims;
        out[2] = 0.f;                   // regs
        out[3] = kld;
    }
}

extern "C" void kernel_launch(void* const* d_in, const int* in_sizes, int n_in,
                              void* d_out, int out_size, void* d_ws, size_t ws_size,
                              hipStream_t stream) {
    const float* ipts    = (const float*)d_in[0];
    const float* trans   = (const float*)d_in[1];
    const float* rot     = (const float*)d_in[2];
    const float* size    = (const float*)d_in[3];
    const float* shp     = (const float*)d_in[4];
    const float* def     = (const float*)d_in[5];
    const float* probs   = (const float*)d_in[6];
    const float* etas    = (const float*)d_in[7];
    const float* omegas  = (const float*)d_in[8];
    const float* mu      = (const float*)d_in[9];
    const float* logvar  = (const float*)d_in[10];
    float* out = (float*)d_out;

    char* ws = (char*)d_ws;
    unsigned int* gmin = (unsigned int*)ws;          // B*M*S*4   = 64000 B
    float* acc    = (float*)(ws + 64000);            // 64 B
    float* wsR    = (float*)(ws + 64064);            // B*M*9*4   = 2880 B
    float4* wsPts = (float4*)(ws + 66944);           // B*M*S*16  = 256000 B

    prep_k<<<B_*M_, 256, 0, stream>>>(rot, size, shp, def, etas, omegas,
                                      wsR, wsPts, gmin, acc);
    fused_k<<<B_*(N_/32), 256, 0, stream>>>(ipts, trans, probs, wsR, wsPts, gmin, acc);
    final_k<<<1, 1024, 0, stream>>>(gmin, probs, mu, logvar, acc, out);
}

// Round 3
// 53.363 us; speedup vs baseline: 1.8515x; 1.3446x over previous
//
#include <hip/hip_runtime.h>
#include <math.h>

#define B_ 8
#define M_ 10
#define S_ 200
#define N_ 2048
#define L_ 128
#define BETA_ 0.01f
#define EPS_ 1e-6f
#define INF_U 0x7F7F7F7Fu

#define PCL_BLOCKS  (B_ * (N_ / 32))        // 512
#define SMIN_BLOCKS (B_ * M_ * (N_ / 256))  // 640

__device__ __forceinline__ float fexp_(float x, float p) {
    float s = (x > 0.f) ? 1.f : ((x < 0.f) ? -1.f : 0.f);
    return s * powf(fmaxf(fabsf(x), EPS_), p);
}

// ---------------------------------------------------------------------------
// Kernel 0: rotation matrices + deformed surface points + ws init (gmin, acc)
// grid: 80 blocks x 256
// ---------------------------------------------------------------------------
__global__ void prep_k(const float* __restrict__ rot, const float* __restrict__ size,
                       const float* __restrict__ shp, const float* __restrict__ def,
                       const float* __restrict__ etas, const float* __restrict__ omegas,
                       float* __restrict__ wsR, float4* __restrict__ wsPts,
                       unsigned int* __restrict__ gmin, float* __restrict__ acc)
{
    int bm = blockIdx.x;      // 0..B*M-1
    int t = threadIdx.x;
    int gid = bm * 256 + t;
    if (gid < B_*M_*S_) gmin[gid] = INF_U;
    if (gid == 0) acc[0] = 0.f;

    if (t == 0) {
        float w = rot[bm*4+0], x = rot[bm*4+1], y = rot[bm*4+2], z = rot[bm*4+3];
        float inv = 1.f / sqrtf(w*w + x*x + y*y + z*z);
        w *= inv; x *= inv; y *= inv; z *= inv;
        float* Rm = wsR + bm*9;
        Rm[0] = 1.f - 2.f*(y*y + z*z); Rm[1] = 2.f*(x*y - w*z);       Rm[2] = 2.f*(x*z + w*y);
        Rm[3] = 2.f*(x*y + w*z);       Rm[4] = 1.f - 2.f*(x*x + z*z); Rm[5] = 2.f*(y*z - w*x);
        Rm[6] = 2.f*(x*z - w*y);       Rm[7] = 2.f*(y*z + w*x);       Rm[8] = 1.f - 2.f*(x*x + y*y);
    }
    if (t < S_) {
        float a1 = size[bm*3+0], a2 = size[bm*3+1], a3 = size[bm*3+2];
        float e1 = shp[bm*2+0],  e2 = shp[bm*2+1];
        float d0 = def[bm*2+0],  d1 = def[bm*2+1];
        float eta = etas[bm*S_+t], om = omegas[bm*S_+t];
        float ce = cosf(eta), se = sinf(eta);
        float co = cosf(om),  so = sinf(om);
        float fce = fexp_(ce, e1), fse = fexp_(se, e1);
        float fco = fexp_(co, e2), fso = fexp_(so, e2);
        float px = a1 * fce * fco;
        float py = a2 * fce * fso;
        float pz = a3 * fse;
        float fr = pz / a3;
        px *= d0*fr + 1.f;
        py *= d1*fr + 1.f;
        wsPts[bm*S_+t] = make_float4(px, py, pz, 0.f);
    }
}

// ---------------------------------------------------------------------------
// Main dispatch: two block roles, one kernel (co-scheduled on the CUs).
//  role PCL  (blockIdx < 512): V = min_s dist, sort over M, Fs -> atomicAdd.
//    s interleaved (s = k*16+sg) => wave reads 16 contiguous float4 = no
//    bank conflicts. No smin work in the inner loop.
//  role SMIN (blockIdx >= 512): per (b,m, 256-n tile): stage rotated Xt in
//    LDS, thread owns s, broadcast reads, global atomicMin once per thread.
// ---------------------------------------------------------------------------
__global__ __launch_bounds__(256) void dist_k(const float* __restrict__ ipts,
                                              const float* __restrict__ trans,
                                              const float* __restrict__ probs,
                                              const float* __restrict__ wsR,
                                              const float4* __restrict__ wsPts,
                                              unsigned int* __restrict__ gmin,
                                              float* __restrict__ acc)
{
    __shared__ float4 sBuf[M_*S_];   // 32 KB (PCL: all pts; SMIN: reuses 4 KB)
    __shared__ float  sR[M_*9];
    __shared__ float  sT[M_*3];
    __shared__ float  sP[M_];
    __shared__ float  sSum[4];

    int t = threadIdx.x;

    if (blockIdx.x < PCL_BLOCKS) {
        // ---------------- PCL role ----------------
        constexpr int CH = N_ / 32;    // 64 chunks of 32 points
        int b = blockIdx.x / CH;
        int chunk = blockIdx.x % CH;

        const float4* gp = wsPts + b*M_*S_;
        for (int i = t; i < M_*S_; i += 256) sBuf[i] = gp[i];
        if (t < M_*9) sR[t] = wsR[b*M_*9 + t];
        if (t < M_*3) sT[t] = trans[b*M_*3 + t];
        if (t < M_)   sP[t] = probs[b*M_ + t];
        __syncthreads();

        int sg = t & 15;             // s-group (bits 0..3 -> within wave)
        int nl = t >> 4;             // 0..15, 2 points each
        int n0 = chunk*32 + nl*2;
        float x0 = ipts[(b*N_+n0)*3 + 0];
        float y0 = ipts[(b*N_+n0)*3 + 1];
        float z0 = ipts[(b*N_+n0)*3 + 2];
        float x1 = ipts[(b*N_+n0+1)*3 + 0];
        float y1 = ipts[(b*N_+n0+1)*3 + 1];
        float z1 = ipts[(b*N_+n0+1)*3 + 2];

        float V0[M_], V1[M_];
        #pragma unroll
        for (int m = 0; m < M_; ++m) {
            float r00 = sR[m*9+0], r01 = sR[m*9+1], r02 = sR[m*9+2];
            float r10 = sR[m*9+3], r11 = sR[m*9+4], r12 = sR[m*9+5];
            float r20 = sR[m*9+6], r21 = sR[m*9+7], r22 = sR[m*9+8];
            float tx = sT[m*3+0], ty = sT[m*3+1], tz = sT[m*3+2];
            float cx = x0 - tx, cy = y0 - ty, cz = z0 - tz;
            float X00 = r00*cx + r01*cy + r02*cz;
            float X01 = r10*cx + r11*cy + r12*cz;
            float X02 = r20*cx + r21*cy + r22*cz;
            cx = x1 - tx; cy = y1 - ty; cz = z1 - tz;
            float X10 = r00*cx + r01*cy + r02*cz;
            float X11 = r10*cx + r11*cy + r12*cz;
            float X12 = r20*cx + r21*cy + r22*cz;
            float vm0 = 3.4e38f, vm1 = 3.4e38f;
            int base = m*S_;
            #pragma unroll
            for (int k = 0; k < 13; ++k) {
                int s = k*16 + sg;                 // interleaved, contiguous per wave
                s = (s > S_-1) ? S_-1 : s;         // dup harmless under min
                float4 p = sBuf[base + s];
                float dx = p.x - X00, dy = p.y - X01, dz = p.z - X02;
                float d0 = dx*dx + dy*dy + dz*dz;
                dx = p.x - X10; dy = p.y - X11; dz = p.z - X12;
                float d1 = dx*dx + dy*dy + dz*dz;
                vm0 = fminf(vm0, d0);
                vm1 = fminf(vm1, d1);
            }
            V0[m] = vm0; V1[m] = vm1;
        }

        // min over the 16 s-groups (bits 0..3 of the lane id)
        #pragma unroll
        for (int m = 0; m < M_; ++m) {
            #pragma unroll
            for (int o = 1; o < 16; o <<= 1) {
                V0[m] = fminf(V0[m], __shfl_xor(V0[m], o));
                V1[m] = fminf(V1[m], __shfl_xor(V1[m], o));
            }
        }

        // sort + Fs weighting for both points (uniform across lanes)
        float sum01 = 0.f;
        {
            float P[M_];
            #pragma unroll
            for (int m = 0; m < M_; ++m) P[m] = sP[m];
            #pragma unroll
            for (int i = 0; i < M_-1; ++i)
                #pragma unroll
                for (int j = 0; j < M_-1-i; ++j)
                    if (V0[j] > V0[j+1]) {
                        float tv = V0[j]; V0[j] = V0[j+1]; V0[j+1] = tv;
                        float tp = P[j];  P[j]  = P[j+1];  P[j+1]  = tp;
                    }
            float cum = 1.f;
            #pragma unroll
            for (int i = 0; i < M_; ++i) { sum01 += P[i] * cum * V0[i]; cum *= (1.f - P[i]); }
        }
        {
            float P[M_];
            #pragma unroll
            for (int m = 0; m < M_; ++m) P[m] = sP[m];
            #pragma unroll
            for (int i = 0; i < M_-1; ++i)
                #pragma unroll
                for (int j = 0; j < M_-1-i; ++j)
                    if (V1[j] > V1[j+1]) {
                        float tv = V1[j]; V1[j] = V1[j+1]; V1[j+1] = tv;
                        float tp = P[j];  P[j]  = P[j+1];  P[j+1]  = tp;
                    }
            float cum = 1.f;
            #pragma unroll
            for (int i = 0; i < M_; ++i) { sum01 += P[i] * cum * V1[i]; cum *= (1.f - P[i]); }
        }

        float contrib = (sg == 0) ? sum01 : 0.f;
        #pragma unroll
        for (int o = 1; o < 64; o <<= 1) contrib += __shfl_xor(contrib, o);

        int wave = t >> 6, lane = t & 63;
        if (lane == 0) sSum[wave] = contrib;
        __syncthreads();
        if (t == 0) atomicAdd(acc, sSum[0] + sSum[1] + sSum[2] + sSum[3]);
    } else {
        // ---------------- SMIN role ----------------
        int idx = blockIdx.x - PCL_BLOCKS;   // 0..639
        int bm = idx >> 3;                   // (b,m)
        int chunk = idx & 7;                 // 256-n tile
        int b = bm / M_;

        float r00 = wsR[bm*9+0], r01 = wsR[bm*9+1], r02 = wsR[bm*9+2];
        float r10 = wsR[bm*9+3], r11 = wsR[bm*9+4], r12 = wsR[bm*9+5];
        float r20 = wsR[bm*9+6], r21 = wsR[bm*9+7], r22 = wsR[bm*9+8];
        float tx = trans[bm*3+0], ty = trans[bm*3+1], tz = trans[bm*3+2];

        int n = chunk*256 + t;
        float x = ipts[(b*N_+n)*3 + 0] - tx;
        float y = ipts[(b*N_+n)*3 + 1] - ty;
        float z = ipts[(b*N_+n)*3 + 2] - tz;
        sBuf[t] = make_float4(r00*x + r01*y + r02*z,
                              r10*x + r11*y + r12*z,
                              r20*x + r21*y + r22*z, 0.f);
        __syncthreads();

        if (t < S_) {
            float4 p = wsPts[bm*S_ + t];
            float vm = 3.4e38f;
            #pragma unroll 8
            for (int j = 0; j < 256; ++j) {    // broadcast reads, conflict-free
                float4 q = sBuf[j];
                float dx = p.x - q.x, dy = p.y - q.y, dz = p.z - q.z;
                float d = dx*dx + dy*dy + dz*dz;
                vm = fminf(vm, d);
            }
            atomicMin(&gmin[bm*S_ + t], __float_as_uint(vm));
        }
    }
}

// ---------------------------------------------------------------------------
// Finalize: prim_to_pcl from gmin, KLD, combine. 1 block x 1024.
// ---------------------------------------------------------------------------
__global__ __launch_bounds__(1024) void final_k(const unsigned int* __restrict__ gmin,
                                                const float* __restrict__ probs,
                                                const float* __restrict__ mu,
                                                const float* __restrict__ logvar,
                                                const float* __restrict__ acc,
                                                float* __restrict__ out)
{
    int t = threadIdx.x;
    float s1 = 0.f;
    for (int i = t; i < B_*M_*S_; i += 1024) {
        int bm = i / S_;
        s1 += __uint_as_float(gmin[i]) * probs[bm];
    }
    float s2 = 0.f;
    for (int i = t; i < B_*L_; i += 1024) {
        float muv = mu[i], lv = logvar[i];
        s2 += -0.5f * (1.f + lv - muv*muv - expf(lv));
    }
    #pragma unroll
    for (int o = 1; o < 64; o <<= 1) {
        s1 += __shfl_xor(s1, o);
        s2 += __shfl_xor(s2, o);
    }
    __shared__ float r1[16], r2[16];
    int wave = t >> 6, lane = t & 63;
    if (lane == 0) { r1[wave] = s1; r2[wave] = s2; }
    __syncthreads();
    if (t == 0) {
        float S1 = 0.f, S2 = 0.f;
        #pragma unroll
        for (int w = 0; w < 16; ++w) { S1 += r1[w]; S2 += r2[w]; }
        float prim_to_pcl = S1 / (float)(B_ * S_);
        float kld = S2 / (float)B_;
        float pcl_to_prim = acc[0] / (float)(B_ * N_);
        float prims = pcl_to_prim + prim_to_pcl;
        out[0] = prims + BETA_ * kld;   // total
        out[1] = prims;
        out[2] = 0.f;                   // regs
        out[3] = kld;
    }
}

extern "C" void kernel_launch(void* const* d_in, const int* in_sizes, int n_in,
                              void* d_out, int out_size, void* d_ws, size_t ws_size,
                              hipStream_t stream) {
    const float* ipts    = (const float*)d_in[0];
    const float* trans   = (const float*)d_in[1];
    const float* rot     = (const float*)d_in[2];
    const float* size    = (const float*)d_in[3];
    const float* shp     = (const float*)d_in[4];
    const float* def     = (const float*)d_in[5];
    const float* probs   = (const float*)d_in[6];
    const float* etas    = (const float*)d_in[7];
    const float* omegas  = (const float*)d_in[8];
    const float* mu      = (const float*)d_in[9];
    const float* logvar  = (const float*)d_in[10];
    float* out = (float*)d_out;

    char* ws = (char*)d_ws;
    unsigned int* gmin = (unsigned int*)ws;          // B*M*S*4   = 64000 B
    float* acc    = (float*)(ws + 64000);            // 64 B
    float* wsR    = (float*)(ws + 64064);            // B*M*9*4   = 2880 B
    float4* wsPts = (float4*)(ws + 66944);           // B*M*S*16  = 256000 B

    prep_k<<<B_*M_, 256, 0, stream>>>(rot, size, shp, def, etas, omegas,
                                      wsR, wsPts, gmin, acc);
    dist_k<<<PCL_BLOCKS + SMIN_BLOCKS, 256, 0, stream>>>(ipts, trans, probs,
                                                         wsR, wsPts, gmin, acc);
    final_k<<<1, 1024, 0, stream>>>(gmin, probs, mu, logvar, acc, out);
}

// Round 4
// 47.982 us; speedup vs baseline: 2.0591x; 1.1122x over previous
//
#include <hip/hip_runtime.h>
#include <math.h>

#define B_ 8
#define M_ 10
#define S_ 200
#define PADS_ 208            // S padded to multiple of 16 (sentinel points)
#define N_ 2048
#define L_ 128
#define BETA_ 0.01f
#define EPS_ 1e-6f
#define INF_U 0x7F7F7F7Fu
#define SENT_ 5.0e18f        // sentinel coord: dist ~7.5e37 < FLT_MAX, > any real

#define PCL_BLOCKS  (B_ * (N_ / 16))        // 1024
#define SMIN_BLOCKS (B_ * M_ * (N_ / 256))  // 640

__device__ __forceinline__ float fexp_(float x, float p) {
    float s = (x > 0.f) ? 1.f : ((x < 0.f) ? -1.f : 0.f);
    return s * powf(fmaxf(fabsf(x), EPS_), p);
}

// ---------------------------------------------------------------------------
// Kernel 0: rotation matrices + padded surface points + ws init (gmin, acc)
// grid: 80 blocks x 256
// ---------------------------------------------------------------------------
__global__ void prep_k(const float* __restrict__ rot, const float* __restrict__ size,
                       const float* __restrict__ shp, const float* __restrict__ def,
                       const float* __restrict__ etas, const float* __restrict__ omegas,
                       float* __restrict__ wsR, float4* __restrict__ wsPts,
                       unsigned int* __restrict__ gmin, float* __restrict__ acc)
{
    int bm = blockIdx.x;      // 0..B*M-1
    int t = threadIdx.x;
    int gid = bm * 256 + t;
    if (gid < B_*M_*S_) gmin[gid] = INF_U;
    if (gid == 0) acc[0] = 0.f;

    if (t == 0) {
        float w = rot[bm*4+0], x = rot[bm*4+1], y = rot[bm*4+2], z = rot[bm*4+3];
        float inv = 1.f / sqrtf(w*w + x*x + y*y + z*z);
        w *= inv; x *= inv; y *= inv; z *= inv;
        float* Rm = wsR + bm*9;
        Rm[0] = 1.f - 2.f*(y*y + z*z); Rm[1] = 2.f*(x*y - w*z);       Rm[2] = 2.f*(x*z + w*y);
        Rm[3] = 2.f*(x*y + w*z);       Rm[4] = 1.f - 2.f*(x*x + z*z); Rm[5] = 2.f*(y*z - w*x);
        Rm[6] = 2.f*(x*z - w*y);       Rm[7] = 2.f*(y*z + w*x);       Rm[8] = 1.f - 2.f*(x*x + y*y);
    }
    if (t < PADS_) {
        if (t < S_) {
            float a1 = size[bm*3+0], a2 = size[bm*3+1], a3 = size[bm*3+2];
            float e1 = shp[bm*2+0],  e2 = shp[bm*2+1];
            float d0 = def[bm*2+0],  d1 = def[bm*2+1];
            float eta = etas[bm*S_+t], om = omegas[bm*S_+t];
            float ce = cosf(eta), se = sinf(eta);
            float co = cosf(om),  so = sinf(om);
            float fce = fexp_(ce, e1), fse = fexp_(se, e1);
            float fco = fexp_(co, e2), fso = fexp_(so, e2);
            float px = a1 * fce * fco;
            float py = a2 * fce * fso;
            float pz = a3 * fse;
            float fr = pz / a3;
            px *= d0*fr + 1.f;
            py *= d1*fr + 1.f;
            wsPts[bm*PADS_+t] = make_float4(px, py, pz, 0.f);
        } else {
            wsPts[bm*PADS_+t] = make_float4(SENT_, SENT_, SENT_, 0.f);  // never wins a min
        }
    }
}

// ---------------------------------------------------------------------------
// Main dispatch, two roles:
//  PCL  (bid < 1024): 16 n per block, 1 n per 16-lane group. pts read from
//    GLOBAL (L2-resident, coalesced 256B per wave-read). Zero LDS. R/T/probs
//    are block-uniform -> scalar loads. V=min_s -> shfl -> sort -> Fs -> acc.
//  SMIN (bid >= 1024): (bm, 256-n tile). All 256 threads stage rotated Xt in
//    LDS; threads t<100 own the s-pair (t, t+100): each ds_read_b128 feeds
//    2 dist evals (halves DS-pipe load). Global atomicMin into gmin.
// ---------------------------------------------------------------------------
__global__ __launch_bounds__(256, 4) void dist_k(const float* __restrict__ ipts,
                                                 const float* __restrict__ trans,
                                                 const float* __restrict__ probs,
                                                 const float* __restrict__ wsR,
                                                 const float4* __restrict__ wsPts,
                                                 unsigned int* __restrict__ gmin,
                                                 float* __restrict__ acc)
{
    __shared__ float4 sQ[256];
    __shared__ float  sSum[4];
    int t = threadIdx.x;

    if (blockIdx.x < PCL_BLOCKS) {
        // ---------------- PCL role ----------------
        constexpr int CH = N_ / 16;     // 128 chunks of 16 points
        int b = blockIdx.x / CH;
        int chunk = blockIdx.x % CH;
        int sg = t & 15;                // s-group (lane bits 0..3)
        int nl = t >> 4;                // 0..15
        int n = chunk*16 + nl;

        float x = ipts[(b*N_+n)*3 + 0];
        float y = ipts[(b*N_+n)*3 + 1];
        float z = ipts[(b*N_+n)*3 + 2];

        const float*  Rb = wsR   + b*M_*9;    // block-uniform -> s_load
        const float*  Tb = trans + b*M_*3;
        const float4* Pb = wsPts + b*M_*PADS_;

        float V[M_];
        #pragma unroll 2
        for (int m = 0; m < M_; ++m) {
            float r00 = Rb[m*9+0], r01 = Rb[m*9+1], r02 = Rb[m*9+2];
            float r10 = Rb[m*9+3], r11 = Rb[m*9+4], r12 = Rb[m*9+5];
            float r20 = Rb[m*9+6], r21 = Rb[m*9+7], r22 = Rb[m*9+8];
            float cx = x - Tb[m*3+0], cy = y - Tb[m*3+1], cz = z - Tb[m*3+2];
            float X0 = r00*cx + r01*cy + r02*cz;
            float X1 = r10*cx + r11*cy + r12*cz;
            float X2 = r20*cx + r21*cy + r22*cz;
            float vm = 3.4e38f;
            const float4* Pm = Pb + m*PADS_ + sg;
            #pragma unroll
            for (int k = 0; k < 13; ++k) {        // covers s = k*16+sg, 0..207
                float4 p = Pm[k*16];              // imm-offset global loads
                float dx = p.x - X0, dy = p.y - X1, dz = p.z - X2;
                float d = dx*dx + dy*dy + dz*dz;
                vm = fminf(vm, d);
            }
            V[m] = vm;
        }

        // min over the 16 s-groups (lane bits 0..3)
        #pragma unroll
        for (int m = 0; m < M_; ++m) {
            #pragma unroll
            for (int o = 1; o < 16; o <<= 1)
                V[m] = fminf(V[m], __shfl_xor(V[m], o));
        }

        // sort + Fs weighting (uniform within each 16-lane group)
        float P[M_];
        #pragma unroll
        for (int m = 0; m < M_; ++m) P[m] = probs[b*M_ + m];
        #pragma unroll
        for (int i = 0; i < M_-1; ++i)
            #pragma unroll
            for (int j = 0; j < M_-1-i; ++j)
                if (V[j] > V[j+1]) {
                    float tv = V[j]; V[j] = V[j+1]; V[j+1] = tv;
                    float tp = P[j]; P[j]  = P[j+1]; P[j+1] = tp;
                }
        float cum = 1.f, sum = 0.f;
        #pragma unroll
        for (int i = 0; i < M_; ++i) { sum += P[i] * cum * V[i]; cum *= (1.f - P[i]); }

        float contrib = (sg == 0) ? sum : 0.f;
        #pragma unroll
        for (int o = 1; o < 64; o <<= 1) contrib += __shfl_xor(contrib, o);

        int wave = t >> 6, lane = t & 63;
        if (lane == 0) sSum[wave] = contrib;
        __syncthreads();
        if (t == 0) atomicAdd(acc, sSum[0] + sSum[1] + sSum[2] + sSum[3]);
    } else {
        // ---------------- SMIN role ----------------
        int idx = blockIdx.x - PCL_BLOCKS;   // 0..639
        int bm = idx >> 3;                   // (b,m)
        int tile = idx & 7;                  // 256-n tile
        int b = bm / M_;

        float r00 = wsR[bm*9+0], r01 = wsR[bm*9+1], r02 = wsR[bm*9+2];
        float r10 = wsR[bm*9+3], r11 = wsR[bm*9+4], r12 = wsR[bm*9+5];
        float r20 = wsR[bm*9+6], r21 = wsR[bm*9+7], r22 = wsR[bm*9+8];
        float tx = trans[bm*3+0], ty = trans[bm*3+1], tz = trans[bm*3+2];

        int n = tile*256 + t;
        float x = ipts[(b*N_+n)*3 + 0] - tx;
        float y = ipts[(b*N_+n)*3 + 1] - ty;
        float z = ipts[(b*N_+n)*3 + 2] - tz;
        sQ[t] = make_float4(r00*x + r01*y + r02*z,
                            r10*x + r11*y + r12*z,
                            r20*x + r21*y + r22*z, 0.f);
        __syncthreads();

        if (t < 100) {                       // s-pair: (t, t+100)
            float4 p0 = wsPts[bm*PADS_ + t];
            float4 p1 = wsPts[bm*PADS_ + t + 100];
            float vm0 = 3.4e38f, vm1 = 3.4e38f;
            #pragma unroll 8
            for (int j = 0; j < 256; ++j) {  // broadcast reads, 2 evals/read
                float4 q = sQ[j];
                float dx = p0.x - q.x, dy = p0.y - q.y, dz = p0.z - q.z;
                float d0 = dx*dx + dy*dy + dz*dz;
                dx = p1.x - q.x; dy = p1.y - q.y; dz = p1.z - q.z;
                float d1 = dx*dx + dy*dy + dz*dz;
                vm0 = fminf(vm0, d0);
                vm1 = fminf(vm1, d1);
            }
            atomicMin(&gmin[bm*S_ + t],       __float_as_uint(vm0));
            atomicMin(&gmin[bm*S_ + t + 100], __float_as_uint(vm1));
        }
    }
}

// ---------------------------------------------------------------------------
// Finalize: prim_to_pcl from gmin (uint4 loads), KLD, combine. 1 block x 1024.
// ---------------------------------------------------------------------------
__global__ __launch_bounds__(1024) void final_k(const unsigned int* __restrict__ gmin,
                                                const float* __restrict__ probs,
                                                const float* __restrict__ mu,
                                                const float* __restrict__ logvar,
                                                const float* __restrict__ acc,
                                                float* __restrict__ out)
{
    int t = threadIdx.x;
    const uint4* g4 = (const uint4*)gmin;    // 4000 uint4; 200%4==0 -> no bm straddle
    float s1 = 0.f;
    for (int i = t; i < (B_*M_*S_)/4; i += 1024) {
        uint4 v = g4[i];
        float p = probs[i / 50];             // bm = (4i)/200 = i/50
        s1 += p * (__uint_as_float(v.x) + __uint_as_float(v.y) +
                   __uint_as_float(v.z) + __uint_as_float(v.w));
    }
    float s2 = 0.f;
    for (int i = t; i < B_*L_; i += 1024) {
        float muv = mu[i], lv = logvar[i];
        s2 += -0.5f * (1.f + lv - muv*muv - expf(lv));
    }
    #pragma unroll
    for (int o = 1; o < 64; o <<= 1) {
        s1 += __shfl_xor(s1, o);
        s2 += __shfl_xor(s2, o);
    }
    __shared__ float r1[16], r2[16];
    int wave = t >> 6, lane = t & 63;
    if (lane == 0) { r1[wave] = s1; r2[wave] = s2; }
    __syncthreads();
    if (t == 0) {
        float S1 = 0.f, S2 = 0.f;
        #pragma unroll
        for (int w = 0; w < 16; ++w) { S1 += r1[w]; S2 += r2[w]; }
        float prim_to_pcl = S1 / (float)(B_ * S_);
        float kld = S2 / (float)B_;
        float pcl_to_prim = acc[0] / (float)(B_ * N_);
        float prims = pcl_to_prim + prim_to_pcl;
        out[0] = prims + BETA_ * kld;   // total
        out[1] = prims;
        out[2] = 0.f;                   // regs
        out[3] = kld;
    }
}

extern "C" void kernel_launch(void* const* d_in, const int* in_sizes, int n_in,
                              void* d_out, int out_size, void* d_ws, size_t ws_size,
                              hipStream_t stream) {
    const float* ipts    = (const float*)d_in[0];
    const float* trans   = (const float*)d_in[1];
    const float* rot     = (const float*)d_in[2];
    const float* size    = (const float*)d_in[3];
    const float* shp     = (const float*)d_in[4];
    const float* def     = (const float*)d_in[5];
    const float* probs   = (const float*)d_in[6];
    const float* etas    = (const float*)d_in[7];
    const float* omegas  = (const float*)d_in[8];
    const float* mu      = (const float*)d_in[9];
    const float* logvar  = (const float*)d_in[10];
    float* out = (float*)d_out;

    char* ws = (char*)d_ws;
    unsigned int* gmin = (unsigned int*)ws;          // B*M*S*4        = 64000 B
    float* acc    = (float*)(ws + 64000);            // 64 B
    float* wsR    = (float*)(ws + 64064);            // B*M*9*4        = 2880 B
    float4* wsPts = (float4*)(ws + 66944);           // B*M*PADS*16    = 266240 B

    prep_k<<<B_*M_, 256, 0, stream>>>(rot, size, shp, def, etas, omegas,
                                      wsR, wsPts, gmin, acc);
    dist_k<<<PCL_BLOCKS + SMIN_BLOCKS, 256, 0, stream>>>(ipts, trans, probs,
                                                         wsR, wsPts, gmin, acc);
    final_k<<<1, 1024, 0, stream>>>(gmin, probs, mu, logvar, acc, out);
}

// Round 5
// 44.241 us; speedup vs baseline: 2.2332x; 1.0845x over previous
//
#include <hip/hip_runtime.h>
#include <math.h>

#define B_ 8
#define M_ 10
#define S_ 200
#define PADS_ 208            // S padded to multiple of 16 (sentinel points)
#define N_ 2048
#define L_ 128
#define BETA_ 0.01f
#define EPS_ 1e-6f
#define INF_U 0x7F7F7F7Fu
#define SENT_ 5.0e18f        // sentinel coord; |p|^2 = 7.5e37 dominates, never wins min

#define NT_ 32                          // n per dist block
#define DIST_BLOCKS (B_ * (N_ / NT_))   // 512

__device__ __forceinline__ float fexp_(float x, float p) {
    float s = (x > 0.f) ? 1.f : ((x < 0.f) ? -1.f : 0.f);
    return s * powf(fmaxf(fabsf(x), EPS_), p);
}

// ---------------------------------------------------------------------------
// Kernel 0: rotation matrices + padded surface points (w = |p|^2) + ws init
// grid: 80 blocks x 256
// ---------------------------------------------------------------------------
__global__ void prep_k(const float* __restrict__ rot, const float* __restrict__ size,
                       const float* __restrict__ shp, const float* __restrict__ def,
                       const float* __restrict__ etas, const float* __restrict__ omegas,
                       float* __restrict__ wsR, float4* __restrict__ wsPts,
                       unsigned int* __restrict__ gmin, float* __restrict__ acc)
{
    int bm = blockIdx.x;      // 0..B*M-1
    int t = threadIdx.x;
    int gid = bm * 256 + t;
    if (gid < B_*M_*S_) gmin[gid] = INF_U;
    if (gid == 0) acc[0] = 0.f;

    if (t == 0) {
        float w = rot[bm*4+0], x = rot[bm*4+1], y = rot[bm*4+2], z = rot[bm*4+3];
        float inv = 1.f / sqrtf(w*w + x*x + y*y + z*z);
        w *= inv; x *= inv; y *= inv; z *= inv;
        float* Rm = wsR + bm*9;
        Rm[0] = 1.f - 2.f*(y*y + z*z); Rm[1] = 2.f*(x*y - w*z);       Rm[2] = 2.f*(x*z + w*y);
        Rm[3] = 2.f*(x*y + w*z);       Rm[4] = 1.f - 2.f*(x*x + z*z); Rm[5] = 2.f*(y*z - w*x);
        Rm[6] = 2.f*(x*z - w*y);       Rm[7] = 2.f*(y*z + w*x);       Rm[8] = 1.f - 2.f*(x*x + y*y);
    }
    if (t < PADS_) {
        if (t < S_) {
            float a1 = size[bm*3+0], a2 = size[bm*3+1], a3 = size[bm*3+2];
            float e1 = shp[bm*2+0],  e2 = shp[bm*2+1];
            float d0 = def[bm*2+0],  d1 = def[bm*2+1];
            float eta = etas[bm*S_+t], om = omegas[bm*S_+t];
            float ce = cosf(eta), se = sinf(eta);
            float co = cosf(om),  so = sinf(om);
            float fce = fexp_(ce, e1), fse = fexp_(se, e1);
            float fco = fexp_(co, e2), fso = fexp_(so, e2);
            float px = a1 * fce * fco;
            float py = a2 * fce * fso;
            float pz = a3 * fse;
            float fr = pz / a3;
            px *= d0*fr + 1.f;
            py *= d1*fr + 1.f;
            wsPts[bm*PADS_+t] = make_float4(px, py, pz, px*px + py*py + pz*pz);
        } else {
            wsPts[bm*PADS_+t] = make_float4(SENT_, SENT_, SENT_, 3.f*SENT_*SENT_);
        }
    }
}

// ---------------------------------------------------------------------------
// Unified dist kernel: ONE pass over dist[b,m,s,n], both reductions in regs.
//   grid = 512 blocks x 256. Block = (b, 32-n tile).
//   Thread sub-tile: sg = lane&15 owns 13 s (s = k*16+sg, padded to 208);
//                    (wave, ngw=lane>>4) owns 2 n.
//   Per m: 26 evals (5 inst each via |p|^2 + |X|^2 - 2 p.X form);
//          V0/V1[m] (min over s) kept in regs -> shfl over sg bits at end;
//          sm[13]   (min over n) -> shfl over lane bits 4,5 -> LDS atomicMin.
//   Block end: sort+Fs per n -> acc; sMin[M][208] -> gmin atomicMin.
// ---------------------------------------------------------------------------
__global__ __launch_bounds__(256) void dist_k(const float* __restrict__ ipts,
                                              const float* __restrict__ trans,
                                              const float* __restrict__ probs,
                                              const float* __restrict__ wsR,
                                              const float4* __restrict__ wsPts,
                                              unsigned int* __restrict__ gmin,
                                              float* __restrict__ acc)
{
    __shared__ unsigned int sMin[M_ * PADS_];   // 8320 B
    __shared__ float sSum[4];
    int t = threadIdx.x;
    int b = blockIdx.x / (N_ / NT_);
    int tile = blockIdx.x % (N_ / NT_);
    int lane = t & 63, wave = t >> 6;
    int sg = lane & 15;          // s-group (lane bits 0..3)
    int ngw = lane >> 4;         // n-subgroup within wave (lane bits 4..5)

    for (int i = t; i < M_*PADS_; i += 256) sMin[i] = INF_U;
    __syncthreads();

    int n0 = tile*NT_ + wave*8 + ngw*2;
    const float* ip = ipts + (size_t)(b*N_ + n0)*3;
    float x0 = ip[0], y0 = ip[1], z0 = ip[2];
    float x1 = ip[3], y1 = ip[4], z1 = ip[5];

    const float*  Rb = wsR   + b*M_*9;    // block-uniform -> scalar loads
    const float*  Tb = trans + b*M_*3;
    const float4* Pb = wsPts + b*M_*PADS_;

    float V0[M_], V1[M_];

    #pragma unroll 2
    for (int m = 0; m < M_; ++m) {
        float r00 = Rb[m*9+0], r01 = Rb[m*9+1], r02 = Rb[m*9+2];
        float r10 = Rb[m*9+3], r11 = Rb[m*9+4], r12 = Rb[m*9+5];
        float r20 = Rb[m*9+6], r21 = Rb[m*9+7], r22 = Rb[m*9+8];
        float tx = Tb[m*3+0], ty = Tb[m*3+1], tz = Tb[m*3+2];

        float cx = x0 - tx, cy = y0 - ty, cz = z0 - tz;
        float X00 = r00*cx + r01*cy + r02*cz;
        float X01 = r10*cx + r11*cy + r12*cz;
        float X02 = r20*cx + r21*cy + r22*cz;
        float A00 = -2.f*X00, A01 = -2.f*X01, A02 = -2.f*X02;
        float c20 = X00*X00 + X01*X01 + X02*X02;

        cx = x1 - tx; cy = y1 - ty; cz = z1 - tz;
        float X10 = r00*cx + r01*cy + r02*cz;
        float X11 = r10*cx + r11*cy + r12*cz;
        float X12 = r20*cx + r21*cy + r22*cz;
        float A10 = -2.f*X10, A11 = -2.f*X11, A12 = -2.f*X12;
        float c21 = X10*X10 + X11*X11 + X12*X12;

        float vm0 = 3.4e38f, vm1 = 3.4e38f;
        float sm[13];
        const float4* Pm = Pb + m*PADS_ + sg;
        #pragma unroll
        for (int k = 0; k < 13; ++k) {
            float4 p = Pm[k*16];                 // imm-offset global loads (L1/L2)
            float w0 = p.w + c20;
            float d0 = fmaf(p.x, A00, fmaf(p.y, A01, fmaf(p.z, A02, w0)));
            float w1 = p.w + c21;
            float d1 = fmaf(p.x, A10, fmaf(p.y, A11, fmaf(p.z, A12, w1)));
            vm0 = fminf(vm0, d0);
            vm1 = fminf(vm1, d1);
            sm[k] = fminf(d0, d1);               // each (m,k) assigned exactly once
        }
        V0[m] = vm0; V1[m] = vm1;

        // smin: reduce over the 16 n-groups = lane bits 4,5 + cross-wave via LDS
        #pragma unroll
        for (int k = 0; k < 13; ++k) {
            float v = sm[k];
            v = fminf(v, __shfl_xor(v, 16));
            v = fminf(v, __shfl_xor(v, 32));
            sm[k] = v;
        }
        if (ngw == 0) {                          // lanes 0..15: one atomic per s
            #pragma unroll
            for (int k = 0; k < 13; ++k)
                atomicMin(&sMin[m*PADS_ + k*16 + sg], __float_as_uint(sm[k]));
        }
    }

    // V: min over the 16 s-groups (lane bits 0..3)
    #pragma unroll
    for (int m = 0; m < M_; ++m) {
        #pragma unroll
        for (int o = 1; o < 16; o <<= 1) {
            V0[m] = fminf(V0[m], __shfl_xor(V0[m], o));
            V1[m] = fminf(V1[m], __shfl_xor(V1[m], o));
        }
    }

    // sort + Fs weighting for both n (uniform within 16-lane group)
    float sum01 = 0.f;
    {
        float P[M_];
        #pragma unroll
        for (int m = 0; m < M_; ++m) P[m] = probs[b*M_ + m];
        #pragma unroll
        for (int i = 0; i < M_-1; ++i)
            #pragma unroll
            for (int j = 0; j < M_-1-i; ++j)
                if (V0[j] > V0[j+1]) {
                    float tv = V0[j]; V0[j] = V0[j+1]; V0[j+1] = tv;
                    float tp = P[j];  P[j]  = P[j+1];  P[j+1]  = tp;
                }
        float cum = 1.f;
        #pragma unroll
        for (int i = 0; i < M_; ++i) { sum01 += P[i] * cum * V0[i]; cum *= (1.f - P[i]); }
    }
    {
        float P[M_];
        #pragma unroll
        for (int m = 0; m < M_; ++m) P[m] = probs[b*M_ + m];
        #pragma unroll
        for (int i = 0; i < M_-1; ++i)
            #pragma unroll
            for (int j = 0; j < M_-1-i; ++j)
                if (V1[j] > V1[j+1]) {
                    float tv = V1[j]; V1[j] = V1[j+1]; V1[j+1] = tv;
                    float tp = P[j];  P[j]  = P[j+1];  P[j+1]  = tp;
                }
        float cum = 1.f;
        #pragma unroll
        for (int i = 0; i < M_; ++i) { sum01 += P[i] * cum * V1[i]; cum *= (1.f - P[i]); }
    }

    float contrib = (sg == 0) ? sum01 : 0.f;     // 4 contributing lanes per wave
    #pragma unroll
    for (int o = 1; o < 64; o <<= 1) contrib += __shfl_xor(contrib, o);
    if (lane == 0) sSum[wave] = contrib;

    __syncthreads();                             // sMin + sSum complete
    if (t == 0) atomicAdd(acc, sSum[0] + sSum[1] + sSum[2] + sSum[3]);

    // merge per-block smin into global (skip sentinel s >= 200)
    for (int i = t; i < M_*PADS_; i += 256) {
        int s = i % PADS_;
        if (s < S_) {
            int m = i / PADS_;
            atomicMin(&gmin[(b*M_ + m)*S_ + s], sMin[i]);
        }
    }
}

// ---------------------------------------------------------------------------
// Finalize: prim_to_pcl from gmin (uint4 loads), KLD, combine. 1 block x 1024.
// ---------------------------------------------------------------------------
__global__ __launch_bounds__(1024) void final_k(const unsigned int* __restrict__ gmin,
                                                const float* __restrict__ probs,
                                                const float* __restrict__ mu,
                                                const float* __restrict__ logvar,
                                                const float* __restrict__ acc,
                                                float* __restrict__ out)
{
    int t = threadIdx.x;
    const uint4* g4 = (const uint4*)gmin;    // 4000 uint4; 200%4==0 -> no bm straddle
    float s1 = 0.f;
    for (int i = t; i < (B_*M_*S_)/4; i += 1024) {
        uint4 v = g4[i];
        float p = probs[i / 50];             // bm = (4i)/200 = i/50
        s1 += p * (__uint_as_float(v.x) + __uint_as_float(v.y) +
                   __uint_as_float(v.z) + __uint_as_float(v.w));
    }
    float s2 = 0.f;
    for (int i = t; i < B_*L_; i += 1024) {
        float muv = mu[i], lv = logvar[i];
        s2 += -0.5f * (1.f + lv - muv*muv - expf(lv));
    }
    #pragma unroll
    for (int o = 1; o < 64; o <<= 1) {
        s1 += __shfl_xor(s1, o);
        s2 += __shfl_xor(s2, o);
    }
    __shared__ float r1[16], r2[16];
    int wave = t >> 6, lane = t & 63;
    if (lane == 0) { r1[wave] = s1; r2[wave] = s2; }
    __syncthreads();
    if (t == 0) {
        float S1 = 0.f, S2 = 0.f;
        #pragma unroll
        for (int w = 0; w < 16; ++w) { S1 += r1[w]; S2 += r2[w]; }
        float prim_to_pcl = S1 / (float)(B_ * S_);
        float kld = S2 / (float)B_;
        float pcl_to_prim = acc[0] / (float)(B_ * N_);
        float prims = pcl_to_prim + prim_to_pcl;
        out[0] = prims + BETA_ * kld;   // total
        out[1] = prims;
        out[2] = 0.f;                   // regs
        out[3] = kld;
    }
}

extern "C" void kernel_launch(void* const* d_in, const int* in_sizes, int n_in,
                              void* d_out, int out_size, void* d_ws, size_t ws_size,
                              hipStream_t stream) {
    const float* ipts    = (const float*)d_in[0];
    const float* trans   = (const float*)d_in[1];
    const float* rot     = (const float*)d_in[2];
    const float* size    = (const float*)d_in[3];
    const float* shp     = (const float*)d_in[4];
    const float* def     = (const float*)d_in[5];
    const float* probs   = (const float*)d_in[6];
    const float* etas    = (const float*)d_in[7];
    const float* omegas  = (const float*)d_in[8];
    const float* mu      = (const float*)d_in[9];
    const float* logvar  = (const float*)d_in[10];
    float* out = (float*)d_out;

    char* ws = (char*)d_ws;
    unsigned int* gmin = (unsigned int*)ws;          // B*M*S*4        = 64000 B
    float* acc    = (float*)(ws + 64000);            // 64 B
    float* wsR    = (float*)(ws + 64064);            // B*M*9*4        = 2880 B
    float4* wsPts = (float4*)(ws + 66944);           // B*M*PADS*16    = 266240 B

    prep_k<<<B_*M_, 256, 0, stream>>>(rot, size, shp, def, etas, omegas,
                                      wsR, wsPts, gmin, acc);
    dist_k<<<DIST_BLOCKS, 256, 0, stream>>>(ipts, trans, probs,
                                            wsR, wsPts, gmin, acc);
    final_k<<<1, 1024, 0, stream>>>(gmin, probs, mu, logvar, acc, out);
}